// Round 2
// baseline (123.673 us; speedup 1.0000x reference)
//
#include <hip/hip_runtime.h>
#include <math.h>

// ---------------- problem constants ----------------
#define NS 3000          // 30*100 samples
#define NF 147           // 3*7*7 encoder feats
#define ND 512
#define NSIG 49          // 7x7 shift classes
#define NSAMP 8          // samples per k_H2s block (375 blocks)
#define NHBLK 375        // 3000 / 8
#define NBLK_VT 1029     // 7 sy * 147 f

// ---------------- ws layout (float offsets) ----------------
#define OFF_WT     0            // 6272 (7*224 float4: w0,w1,i0,i1)
#define OFF_FEATS  6272         // 160
#define OFF_T      236928       // T2[sig][g][f]: 49*49*147 = 352947 -> 589875
#define OFF_G      589952       // 7203 -> 597155
#define OFF_M      598016       // M[147][147] = 21609 -> 619625
#define OFF_ORD    619648       // 3000 ints (sig-sorted sample ids)
// end < 623000 floats = 2.5 MB

// weight of upsample(+reflect,+shift): output pixel p, shift sigma
__device__ __forceinline__ void wt_compute(int sigma, int p, int& i0c, int& i1c,
                                           float& w0, float& w1) {
  int k = p + sigma - 3;
  int r = k < 0 ? -k : (k > 223 ? 446 - k : k);    // np.pad 'reflect'
  float tc = (float)(2 * r - 31) * (1.0f / 64.0f); // (r+0.5)/32 - 0.5, exact
  float fl = floorf(tc);
  int i0 = (int)fl;
  float fr = tc - fl;
  i0c = min(max(i0, 0), 6);
  i1c = min(max(i0 + 1, 0), 6);
  w0 = 1.0f - fr;
  w1 = fr;
}

// Fused initV + T (+ M = Wenc@Wenc^T tiles + sig bucket-sort).
// blocks: [0,1029) VT work; 1029 WT; [1030,1058] zero G; 1059 sort;
//         [1060,1114] M tiles (10x10 upper triangle = 55)
__global__ void __launch_bounds__(256) k_VT(const float* __restrict__ x,
                                            const float* __restrict__ Wenc,
                                            const int* __restrict__ shx,
                                            const int* __restrict__ shy,
                                            float* __restrict__ ws) {
  __shared__ float sX[32][33];       // padded: V-stage reads column-wise
  __shared__ float sV[32][8];        // [y0][gx]
  __shared__ float4 sWX[32];         // x-weights for this (sy, cx)
  __shared__ float4 sWY[7][32];      // y-weights [sx][y0] for this cy
  __shared__ float red[4];
  __shared__ float sA[16][33], sB[16][33];  // M tiles
  __shared__ int hist[64];                  // sort histogram/starts

  int b = blockIdx.x;
  int t = threadIdx.x;
  if (b >= NBLK_VT) {
    if (b == NBLK_VT) {
      float4* WT = (float4*)(ws + OFF_WT);
      for (int e = t; e < 7 * 224; e += 256) {
        int sigma = e / 224, p = e % 224;
        int i0c, i1c; float w0, w1;
        wt_compute(sigma, p, i0c, i1c, w0, w1);
        WT[e] = make_float4(w0, w1, __int_as_float(i0c), __int_as_float(i1c));
      }
    } else if (b <= NBLK_VT + 29) {
      int e = (b - NBLK_VT - 1) * 256 + t;
      if (e < 3 * 2401) ws[OFF_G + e] = 0.f;
    } else if (b == NBLK_VT + 30) {
      // bucket-sort sample ids by sig (G accumulation is order-free)
      if (t < 49) hist[t] = 0;
      __syncthreads();
      for (int i = t; i < NS; i += 256)
        atomicAdd(&hist[shx[i] * 7 + shy[i]], 1);
      __syncthreads();
      if (t == 0) {
        int run = 0;
        for (int s2 = 0; s2 < 49; ++s2) { int c2 = hist[s2]; hist[s2] = run; run += c2; }
      }
      __syncthreads();
      int* ord = (int*)ws + OFF_ORD;
      for (int i = t; i < NS; i += 256) {
        int s2 = shx[i] * 7 + shy[i];
        ord[atomicAdd(&hist[s2], 1)] = i;
      }
    } else {
      // M tile (bi,bj), bi<=bj, 16x16 entries, K=512 in chunks of 32
      int mm = b - (NBLK_VT + 31);
      int bi = 0;
      while (mm >= 10 - bi) { mm -= 10 - bi; ++bi; }
      int bj = bi + mm;
      int ti = t >> 4, tj = t & 15;
      float acc = 0.f;
      for (int d0 = 0; d0 < ND; d0 += 32) {
        for (int e = t; e < 512; e += 256) {
          int r = e >> 5, cc = e & 31;
          int ia = bi * 16 + r, ja = bj * 16 + r;
          sA[r][cc] = (ia < NF) ? Wenc[ia * ND + d0 + cc] : 0.f;
          sB[r][cc] = (ja < NF) ? Wenc[ja * ND + d0 + cc] : 0.f;
        }
        __syncthreads();
        #pragma unroll
        for (int dd = 0; dd < 32; ++dd) acc = fmaf(sA[ti][dd], sB[tj][dd], acc);
        __syncthreads();
      }
      int i = bi * 16 + ti, j = bj * 16 + tj;
      if (i < NF && j < NF) {
        ws[OFF_M + i * NF + j] = acc;
        if (bi != bj) ws[OFF_M + j * NF + i] = acc;
      }
    }
    return;
  }

  int f = b % NF;
  int sy = b / NF;
  int c = f / 49, rem = f % 49, cy = rem / 7, cx = rem % 7;

  // ---- load x tile (+ per-thread partial sum for feats) ----
  const float* xb = x + (c * 224 + cy * 32) * 224 + cx * 32;
  float psum = 0.f;
  for (int idx = t; idx < 1024; idx += 256) {
    int yy = idx >> 5, xx = idx & 31;
    float v = xb[yy * 224 + xx];
    sX[yy][xx] = v;
    psum += v;
  }

  // ---- weight tables ----
  if (t < 32) {
    int i0, i1; float w0, w1;
    wt_compute(sy, cx * 32 + t, i0, i1, w0, w1);
    sWX[t] = make_float4(w0, w1, __int_as_float(i0), __int_as_float(i1));
  } else if (t < 32 + 224) {
    int e = t - 32;
    int sx = e >> 5, y0 = e & 31;
    int i0, i1; float w0, w1;
    wt_compute(sx, cy * 32 + y0, i0, i1, w0, w1);
    sWY[sx][y0] = make_float4(w0, w1, __int_as_float(i0), __int_as_float(i1));
  }

  // ---- feats (h* input): only once per f, in the sy==0 blocks ----
  if (sy == 0) {
    float acc = psum;
    for (int off = 32; off; off >>= 1) acc += __shfl_down(acc, off);
    int wave = t >> 6, lane = t & 63;
    if (lane == 0) red[wave] = acc;
  }
  __syncthreads();
  if (sy == 0 && t == 0)
    ws[OFF_FEATS + f] = (red[0] + red[1] + red[2] + red[3]) * (1.0f / 1024.0f);

  // ---- V stage: sV[y0][gx] = sum_x0 wx * sX[y0][x0] ----
  if (t < 224) {
    int y0 = t / 7, gx = t % 7;
    float acc = 0.f;
    #pragma unroll
    for (int x0 = 0; x0 < 32; ++x0) {
      float4 wt = sWX[x0];
      int i0 = __float_as_int(wt.z), i1 = __float_as_int(wt.w);
      float w = (gx == i0 ? wt.x : 0.f) + (gx == i1 ? wt.y : 0.f);
      acc = fmaf(w, sX[y0][x0], acc);
    }
    sV[y0][gx] = acc;
  }
  __syncthreads();

  // ---- T2 stage: 343 outputs (sx, gy, gx) ----
  for (int e = t; e < 343; e += 256) {
    int sx = e / 49, r2 = e % 49, gy = r2 / 7, gx = r2 % 7;
    float acc = 0.f;
    #pragma unroll
    for (int y0 = 0; y0 < 32; ++y0) {
      float4 wt = sWY[sx][y0];
      int i0 = __float_as_int(wt.z), i1 = __float_as_int(wt.w);
      float w = (gy == i0 ? wt.x : 0.f) + (gy == i1 ? wt.y : 0.f);
      acc = fmaf(w, sV[y0][gx], acc);
    }
    ws[OFF_T + ((sx * 7 + sy) * 49 + gy * 7 + gx) * NF + f] = acc * (1.0f / 1024.0f);
  }
}

// v2: F = T2[sig]@g (LDS), then s via quadratic forms with M = Wenc Wenc^T:
//   q_r = M @ f_r  (f_r = sample F-row; row 8 = feats)
//   num_r = q_r . feats ; |h_r|^2 = q_r . f_r ; |h*|^2 = q_feats . feats
// No Wenc stream (was 226 MB of L2). Samples sig-sorted -> T2 slab L1-resident,
// single-sig blocks do accumulate-then-atomic flush.
__global__ void __launch_bounds__(256) k_H2s(const float* __restrict__ grids,
                                             const int* __restrict__ shx,
                                             const int* __restrict__ shy,
                                             float* __restrict__ ws) {
  __shared__ float sF[NSAMP + 1][NF];   // rows 0..7 samples, row 8 = feats
  __shared__ float sGr[NSAMP][49];
  __shared__ int   sSig[NSAMP];
  __shared__ int   sId[NSAMP];
  __shared__ float sRed[2 * NSAMP + 1][4];
  __shared__ float sS[NSAMP];
  __shared__ int   sUni;
  int t = threadIdx.x;
  int b = blockIdx.x;
  int i0s = b * NSAMP;
  const int* ord = (const int*)ws + OFF_ORD;
  if (t < NSAMP) {
    int id = ord[i0s + t];
    sId[t] = id;
    sSig[t] = shx[id] * 7 + shy[id];
  }
  if (t < NF) sF[NSAMP][t] = ws[OFF_FEATS + t];
  __syncthreads();
  for (int e = t; e < NSAMP * 49; e += 256) {
    int r = e / 49, k = e % 49;
    sGr[r][k] = grids[sId[r] * 49 + k];
  }
  if (t == 0) {
    int u = 1;
    for (int r = 1; r < NSAMP; ++r) u &= (sSig[r] == sSig[0]);
    sUni = u;
  }
  __syncthreads();
  // ---- F-stage ----
  for (int idx = t; idx < NF * NSAMP; idx += 256) {
    int r = idx / NF, f = idx - r * NF;
    const float* T2 = ws + OFF_T + sSig[r] * (49 * NF) + f;
    const float* gr = sGr[r];
    float acc = 0.f;
    #pragma unroll
    for (int g = 0; g < 49; ++g) acc = fmaf(T2[g * NF], gr[g], acc);
    sF[r][f] = acc;
  }
  __syncthreads();
  // ---- M-stage: q[r][t] = sum_j M[j][t] * sF[r][j] (coalesced M columns) ----
  int tcl = (t < NF) ? t : 0;
  float msk = (t < NF) ? 1.f : 0.f;
  const float* Mcol = ws + OFF_M + ((t < NF) ? t : NF - 1);
  float q[NSAMP + 1];
  #pragma unroll
  for (int r = 0; r <= NSAMP; ++r) q[r] = 0.f;
  #pragma unroll 7
  for (int j = 0; j < NF; ++j) {
    float mv = Mcol[j * NF];
    #pragma unroll
    for (int r = 0; r <= NSAMP; ++r) q[r] = fmaf(mv, sF[r][j], q[r]);
  }
  // ---- reductions: num_r, den_r, |h*|^2 ----
  int wave = t >> 6, lane = t & 63;
  float ft = msk * sF[NSAMP][tcl];
  #pragma unroll
  for (int r = 0; r < NSAMP; ++r) {
    float pn = q[r] * ft;
    float pd = msk * q[r] * sF[r][tcl];
    for (int off = 32; off; off >>= 1) {
      pn += __shfl_down(pn, off);
      pd += __shfl_down(pd, off);
    }
    if (lane == 0) { sRed[r][wave] = pn; sRed[NSAMP + r][wave] = pd; }
  }
  {
    float ph = q[NSAMP] * ft;
    for (int off = 32; off; off >>= 1) ph += __shfl_down(ph, off);
    if (lane == 0) sRed[2 * NSAMP][wave] = ph;
  }
  __syncthreads();
  if (t < NSAMP) {
    float num = sRed[t][0] + sRed[t][1] + sRed[t][2] + sRed[t][3];
    float dq  = sRed[NSAMP + t][0] + sRed[NSAMP + t][1] + sRed[NSAMP + t][2] + sRed[NSAMP + t][3];
    float hs  = sRed[2 * NSAMP][0] + sRed[2 * NSAMP][1] + sRed[2 * NSAMP][2] + sRed[2 * NSAMP][3];
    dq = fmaxf(dq, 0.f);
    hs = fmaxf(hs, 0.f);
    sS[t] = num / fmaxf(sqrtf(hs) * sqrtf(dq), 1e-8f);
  }
  __syncthreads();
  // ---- flush into G ----
  if (sUni) {
    // all samples same sig: accumulate across r, one atomic per (p,k)
    for (int e = t; e < 3 * 49; e += 256) {
      int k = e % 49, p = e / 49;
      float acc = 0.f;
      #pragma unroll
      for (int r = 0; r < NSAMP; ++r) {
        float gv = sGr[r][k];
        float s = sS[r];
        float add = (p == 0) ? 1.f : ((p == 1) ? s : s * s);
        acc += (gv != 0.f) ? add : 0.f;
      }
      if (acc != 0.f) atomicAdd(&ws[OFF_G + p * 2401 + sSig[0] * 49 + k], acc);
    }
  } else {
    for (int e = t; e < NSAMP * 3 * 49; e += 256) {
      int k = e % 49;
      int rp = e / 49;
      int r = rp / 3, p = rp - r * 3;
      float gv = sGr[r][k];
      if (gv != 0.f) {
        float s = sS[r];
        float add = (p == 0) ? 1.f : ((p == 1) ? s : s * s);
        atomicAdd(&ws[OFF_G + p * 2401 + sSig[r] * 49 + k], add);
      }
    }
  }
}

// per-px-column C slice + final Welford output (one block per px)
__global__ void __launch_bounds__(256) k_CO(const float* __restrict__ ws,
                                            float* __restrict__ out) {
  __shared__ float Gl[3 * 2401];
  __shared__ float sC[NF];          // [k][sx][gy]
  int b = blockIdx.x;               // px
  int t = threadIdx.x;
  for (int e = t; e < 3 * 2401; e += 256) Gl[e] = ws[OFF_G + e];
  __syncthreads();
  const float4* WT = (const float4*)(ws + OFF_WT);
  if (t < NF) {
    int k = t / 49, r = t - k * 49;
    int sx = r / 7, gy = r % 7;
    float acc = 0.f;
    for (int sy = 0; sy < 7; ++sy) {
      float4 wt = WT[sy * 224 + b];
      int i0 = __float_as_int(wt.z), i1 = __float_as_int(wt.w);
      int base = k * 2401 + (sx * 7 + sy) * 49 + gy * 7;
      acc += wt.x * Gl[base + i0] + wt.y * Gl[base + i1];
    }
    sC[t] = acc;
  }
  __syncthreads();
  if (t < 224) {
    int py = t;
    float S0 = 0.f, S1 = 0.f, S2 = 0.f;
    for (int sx = 0; sx < 7; ++sx) {
      float4 wt = WT[sx * 224 + py];
      int i0 = __float_as_int(wt.z), i1 = __float_as_int(wt.w);
      int base = sx * 7;
      S0 += wt.x * sC[base + i0]      + wt.y * sC[base + i1];
      S1 += wt.x * sC[49 + base + i0] + wt.y * sC[49 + base + i1];
      S2 += wt.x * sC[98 + base + i0] + wt.y * sC[98 + base + i1];
    }
    float W = 1e-10f + S0;
    float R = S1 / W;
    float U = S2 - S1 * S1 / W;
    out[py * 224 + b] = R;
    out[224 * 224 + py * 224 + b] = U / (W - 1.0f);
  }
}

extern "C" void kernel_launch(void* const* d_in, const int* in_sizes, int n_in,
                              void* d_out, int out_size, void* d_ws, size_t ws_size,
                              hipStream_t stream) {
  const float* x     = (const float*)d_in[0];
  const float* Wenc  = (const float*)d_in[1];
  const float* grids = (const float*)d_in[2];
  const int*   shx   = (const int*)d_in[3];
  const int*   shy   = (const int*)d_in[4];
  float* out = (float*)d_out;
  float* ws  = (float*)d_ws;

  // 1029 work + 1 WT + 29 G-zero + 1 sort + 55 M-tile blocks
  k_VT<<<NBLK_VT + 31 + 55, 256, 0, stream>>>(x, Wenc, shx, shy, ws);
  k_H2s<<<NHBLK, 256, 0, stream>>>(grids, shx, shy, ws);
  k_CO<<<224, 256, 0, stream>>>(ws, out);
}

// Round 3
// 115.063 us; speedup vs baseline: 1.0748x; 1.0748x over previous
//
#include <hip/hip_runtime.h>
#include <math.h>

// ---------------- problem constants ----------------
#define NS 3000          // 30*100 samples
#define NF 147           // 3*7*7 encoder feats
#define ND 512
#define NSIG 49          // 7x7 shift classes
#define NSAMP 4          // samples per k_H2s block (750 blocks, ~3/CU)
#define NHBLK 750        // 3000 / 4
#define NBLK_VT 1029     // 7 sy * 147 f

// ---------------- ws layout (float offsets) ----------------
#define OFF_WT     0            // 6272 (7*224 float4: w0,w1,i0,i1)
#define OFF_FEATS  6272         // 160
#define OFF_T      236928       // T2[sig][g][f]: 49*49*147 = 352947 -> 589875
#define OFF_G      589952       // 7203 -> 597155
#define OFF_M      598016       // M[147][147] = 21609 -> 619625
#define OFF_ORD    619648       // 3000 ints (sig-sorted sample ids)
// end < 623000 floats = 2.5 MB

// weight of upsample(+reflect,+shift): output pixel p, shift sigma
__device__ __forceinline__ void wt_compute(int sigma, int p, int& i0c, int& i1c,
                                           float& w0, float& w1) {
  int k = p + sigma - 3;
  int r = k < 0 ? -k : (k > 223 ? 446 - k : k);    // np.pad 'reflect'
  float tc = (float)(2 * r - 31) * (1.0f / 64.0f); // (r+0.5)/32 - 0.5, exact
  float fl = floorf(tc);
  int i0 = (int)fl;
  float fr = tc - fl;
  i0c = min(max(i0, 0), 6);
  i1c = min(max(i0 + 1, 0), 6);
  w0 = 1.0f - fr;
  w1 = fr;
}

// Fused initV + T (+ M = Wenc@Wenc^T tiles + sig bucket-sort).
// blocks: [0,1029) VT work; 1029 WT; [1030,1058] zero G; 1059 sort;
//         [1060,1114] M tiles (10x10 upper triangle = 55)
__global__ void __launch_bounds__(256) k_VT(const float* __restrict__ x,
                                            const float* __restrict__ Wenc,
                                            const int* __restrict__ shx,
                                            const int* __restrict__ shy,
                                            float* __restrict__ ws) {
  __shared__ float sX[32][33];       // padded: V-stage reads column-wise
  __shared__ float sV[32][8];        // [y0][gx]
  __shared__ float4 sWX[32];         // x-weights for this (sy, cx)
  __shared__ float4 sWY[7][32];      // y-weights [sx][y0] for this cy
  __shared__ float red[4];
  __shared__ float sA[16][33], sB[16][33];  // M tiles
  __shared__ int hist[64];                  // sort histogram/starts

  int b = blockIdx.x;
  int t = threadIdx.x;
  if (b >= NBLK_VT) {
    if (b == NBLK_VT) {
      float4* WT = (float4*)(ws + OFF_WT);
      for (int e = t; e < 7 * 224; e += 256) {
        int sigma = e / 224, p = e % 224;
        int i0c, i1c; float w0, w1;
        wt_compute(sigma, p, i0c, i1c, w0, w1);
        WT[e] = make_float4(w0, w1, __int_as_float(i0c), __int_as_float(i1c));
      }
    } else if (b <= NBLK_VT + 29) {
      int e = (b - NBLK_VT - 1) * 256 + t;
      if (e < 3 * 2401) ws[OFF_G + e] = 0.f;
    } else if (b == NBLK_VT + 30) {
      // bucket-sort sample ids by sig (G accumulation is order-free)
      if (t < 49) hist[t] = 0;
      __syncthreads();
      for (int i = t; i < NS; i += 256)
        atomicAdd(&hist[shx[i] * 7 + shy[i]], 1);
      __syncthreads();
      if (t == 0) {
        int run = 0;
        for (int s2 = 0; s2 < 49; ++s2) { int c2 = hist[s2]; hist[s2] = run; run += c2; }
      }
      __syncthreads();
      int* ord = (int*)ws + OFF_ORD;
      for (int i = t; i < NS; i += 256) {
        int s2 = shx[i] * 7 + shy[i];
        ord[atomicAdd(&hist[s2], 1)] = i;
      }
    } else {
      // M tile (bi,bj), bi<=bj, 16x16 entries, K=512 in chunks of 32
      int mm = b - (NBLK_VT + 31);
      int bi = 0;
      while (mm >= 10 - bi) { mm -= 10 - bi; ++bi; }
      int bj = bi + mm;
      int ti = t >> 4, tj = t & 15;
      float acc = 0.f;
      for (int d0 = 0; d0 < ND; d0 += 32) {
        for (int e = t; e < 512; e += 256) {
          int r = e >> 5, cc = e & 31;
          int ia = bi * 16 + r, ja = bj * 16 + r;
          sA[r][cc] = (ia < NF) ? Wenc[ia * ND + d0 + cc] : 0.f;
          sB[r][cc] = (ja < NF) ? Wenc[ja * ND + d0 + cc] : 0.f;
        }
        __syncthreads();
        #pragma unroll
        for (int dd = 0; dd < 32; ++dd) acc = fmaf(sA[ti][dd], sB[tj][dd], acc);
        __syncthreads();
      }
      int i = bi * 16 + ti, j = bj * 16 + tj;
      if (i < NF && j < NF) {
        ws[OFF_M + i * NF + j] = acc;
        if (bi != bj) ws[OFF_M + j * NF + i] = acc;
      }
    }
    return;
  }

  int f = b % NF;
  int sy = b / NF;
  int c = f / 49, rem = f % 49, cy = rem / 7, cx = rem % 7;

  // ---- load x tile (+ per-thread partial sum for feats) ----
  const float* xb = x + (c * 224 + cy * 32) * 224 + cx * 32;
  float psum = 0.f;
  for (int idx = t; idx < 1024; idx += 256) {
    int yy = idx >> 5, xx = idx & 31;
    float v = xb[yy * 224 + xx];
    sX[yy][xx] = v;
    psum += v;
  }

  // ---- weight tables ----
  if (t < 32) {
    int i0, i1; float w0, w1;
    wt_compute(sy, cx * 32 + t, i0, i1, w0, w1);
    sWX[t] = make_float4(w0, w1, __int_as_float(i0), __int_as_float(i1));
  } else if (t < 32 + 224) {
    int e = t - 32;
    int sx = e >> 5, y0 = e & 31;
    int i0, i1; float w0, w1;
    wt_compute(sx, cy * 32 + y0, i0, i1, w0, w1);
    sWY[sx][y0] = make_float4(w0, w1, __int_as_float(i0), __int_as_float(i1));
  }

  // ---- feats (h* input): only once per f, in the sy==0 blocks ----
  if (sy == 0) {
    float acc = psum;
    for (int off = 32; off; off >>= 1) acc += __shfl_down(acc, off);
    int wave = t >> 6, lane = t & 63;
    if (lane == 0) red[wave] = acc;
  }
  __syncthreads();
  if (sy == 0 && t == 0)
    ws[OFF_FEATS + f] = (red[0] + red[1] + red[2] + red[3]) * (1.0f / 1024.0f);

  // ---- V stage: sV[y0][gx] = sum_x0 wx * sX[y0][x0] ----
  if (t < 224) {
    int y0 = t / 7, gx = t % 7;
    float acc = 0.f;
    #pragma unroll
    for (int x0 = 0; x0 < 32; ++x0) {
      float4 wt = sWX[x0];
      int i0 = __float_as_int(wt.z), i1 = __float_as_int(wt.w);
      float w = (gx == i0 ? wt.x : 0.f) + (gx == i1 ? wt.y : 0.f);
      acc = fmaf(w, sX[y0][x0], acc);
    }
    sV[y0][gx] = acc;
  }
  __syncthreads();

  // ---- T2 stage: 343 outputs (sx, gy, gx) ----
  for (int e = t; e < 343; e += 256) {
    int sx = e / 49, r2 = e % 49, gy = r2 / 7, gx = r2 % 7;
    float acc = 0.f;
    #pragma unroll
    for (int y0 = 0; y0 < 32; ++y0) {
      float4 wt = sWY[sx][y0];
      int i0 = __float_as_int(wt.z), i1 = __float_as_int(wt.w);
      float w = (gy == i0 ? wt.x : 0.f) + (gy == i1 ? wt.y : 0.f);
      acc = fmaf(w, sV[y0][gx], acc);
    }
    ws[OFF_T + ((sx * 7 + sy) * 49 + gy * 7 + gx) * NF + f] = acc * (1.0f / 1024.0f);
  }
}

// v3: R1 loop shape + M-trick. sF[f][8] rows: r0..r3 samples, idx4 = feats.
// Per f: 1 coalesced M-column load (4B) + ds_read_b128 + scalar LDS + 5 fma.
// s via quadratic forms (no Wenc stream): q_r = M@f_r, num = q_r.feats,
// |h_r|^2 = q_r.f_r, |h*|^2 = q_feats.feats. Samples sig-sorted.
__global__ void __launch_bounds__(256) k_H2s(const float* __restrict__ grids,
                                             const int* __restrict__ shx,
                                             const int* __restrict__ shy,
                                             float* __restrict__ ws) {
  __shared__ __align__(16) float sF[NF][8];  // [f][r0..r3, feats, pad]
  __shared__ float sGr[NSAMP][49];
  __shared__ int   sSig[NSAMP];
  __shared__ int   sId[NSAMP];
  __shared__ float sRed[2 * NSAMP + 1][4];
  __shared__ float sS[NSAMP];
  __shared__ int   sUni;
  int t = threadIdx.x;
  int b = blockIdx.x;
  int i0s = b * NSAMP;
  const int* ord = (const int*)ws + OFF_ORD;
  if (t < NSAMP) {
    int id = ord[i0s + t];
    sId[t] = id;
    sSig[t] = shx[id] * 7 + shy[id];
  }
  if (t < NF) sF[t][4] = ws[OFF_FEATS + t];
  if (t == 0) sUni = 1;
  __syncthreads();
  for (int e = t; e < NSAMP * 49; e += 256) {
    int r = e / 49, k = e % 49;
    sGr[r][k] = grids[sId[r] * 49 + k];
  }
  if (t < NSAMP && t > 0 && sSig[t] != sSig[0]) sUni = 0;
  __syncthreads();
  // ---- F-stage: sF[f][r] = T2[sig_r][:, f] . grid_r ----
  for (int idx = t; idx < NF * NSAMP; idx += 256) {
    int r = idx / NF, f = idx - r * NF;
    const float* T2 = ws + OFF_T + sSig[r] * (49 * NF) + f;
    const float* gr = sGr[r];
    float acc = 0.f;
    #pragma unroll
    for (int g = 0; g < 49; ++g) acc = fmaf(T2[g * NF], gr[g], acc);
    sF[f][r] = acc;
  }
  __syncthreads();
  // ---- M-stage: q[r] = sum_f M[f][t] * sF[f][r]  (R1-style loop shape) ----
  int tcl = (t < NF) ? t : 0;
  float msk = (t < NF) ? 1.f : 0.f;
  const float* Mcol = ws + OFF_M + tcl;
  float q0 = 0.f, q1 = 0.f, q2 = 0.f, q3 = 0.f, qh = 0.f;
  const float4* sF4 = (const float4*)sF;   // row f -> sF4[2*f]
  #pragma unroll 7
  for (int f = 0; f < NF; ++f) {
    float mv = Mcol[f * NF];
    float4 a4 = sF4[2 * f];
    float af = sF[f][4];
    q0 = fmaf(mv, a4.x, q0);
    q1 = fmaf(mv, a4.y, q1);
    q2 = fmaf(mv, a4.z, q2);
    q3 = fmaf(mv, a4.w, q3);
    qh = fmaf(mv, af, qh);
  }
  // ---- reductions: num_r, den_r, |h*|^2 ----
  int wave = t >> 6, lane = t & 63;
  float4 ft4 = ((const float4*)sF)[2 * tcl];
  float fth = sF[tcl][4] * msk;
  float fr[NSAMP] = {ft4.x, ft4.y, ft4.z, ft4.w};
  float q[NSAMP] = {q0, q1, q2, q3};
  #pragma unroll
  for (int r = 0; r < NSAMP; ++r) {
    float pn = q[r] * fth;
    float pd = msk * q[r] * fr[r];
    for (int off = 32; off; off >>= 1) {
      pn += __shfl_down(pn, off);
      pd += __shfl_down(pd, off);
    }
    if (lane == 0) { sRed[r][wave] = pn; sRed[NSAMP + r][wave] = pd; }
  }
  {
    float ph = qh * fth;
    for (int off = 32; off; off >>= 1) ph += __shfl_down(ph, off);
    if (lane == 0) sRed[2 * NSAMP][wave] = ph;
  }
  __syncthreads();
  if (t < NSAMP) {
    float num = sRed[t][0] + sRed[t][1] + sRed[t][2] + sRed[t][3];
    float dq  = sRed[NSAMP + t][0] + sRed[NSAMP + t][1] + sRed[NSAMP + t][2] + sRed[NSAMP + t][3];
    float hs  = sRed[2 * NSAMP][0] + sRed[2 * NSAMP][1] + sRed[2 * NSAMP][2] + sRed[2 * NSAMP][3];
    dq = fmaxf(dq, 0.f);
    hs = fmaxf(hs, 0.f);
    sS[t] = num / fmaxf(sqrtf(hs) * sqrtf(dq), 1e-8f);
  }
  __syncthreads();
  // ---- flush into G ----
  if (sUni) {
    // all samples same sig: accumulate across r, one atomic per (p,k)
    for (int e = t; e < 3 * 49; e += 256) {
      int k = e % 49, p = e / 49;
      float acc = 0.f;
      #pragma unroll
      for (int r = 0; r < NSAMP; ++r) {
        float gv = sGr[r][k];
        float s = sS[r];
        float add = (p == 0) ? 1.f : ((p == 1) ? s : s * s);
        acc += (gv != 0.f) ? add : 0.f;
      }
      if (acc != 0.f) atomicAdd(&ws[OFF_G + p * 2401 + sSig[0] * 49 + k], acc);
    }
  } else {
    for (int e = t; e < NSAMP * 3 * 49; e += 256) {
      int k = e % 49;
      int rp = e / 49;
      int r = rp / 3, p = rp - r * 3;
      float gv = sGr[r][k];
      if (gv != 0.f) {
        float s = sS[r];
        float add = (p == 0) ? 1.f : ((p == 1) ? s : s * s);
        atomicAdd(&ws[OFF_G + p * 2401 + sSig[r] * 49 + k], add);
      }
    }
  }
}

// per-px-column C slice + final Welford output (one block per px)
__global__ void __launch_bounds__(256) k_CO(const float* __restrict__ ws,
                                            float* __restrict__ out) {
  __shared__ float Gl[3 * 2401];
  __shared__ float sC[NF];          // [k][sx][gy]
  int b = blockIdx.x;               // px
  int t = threadIdx.x;
  for (int e = t; e < 3 * 2401; e += 256) Gl[e] = ws[OFF_G + e];
  __syncthreads();
  const float4* WT = (const float4*)(ws + OFF_WT);
  if (t < NF) {
    int k = t / 49, r = t - k * 49;
    int sx = r / 7, gy = r % 7;
    float acc = 0.f;
    for (int sy = 0; sy < 7; ++sy) {
      float4 wt = WT[sy * 224 + b];
      int i0 = __float_as_int(wt.z), i1 = __float_as_int(wt.w);
      int base = k * 2401 + (sx * 7 + sy) * 49 + gy * 7;
      acc += wt.x * Gl[base + i0] + wt.y * Gl[base + i1];
    }
    sC[t] = acc;
  }
  __syncthreads();
  if (t < 224) {
    int py = t;
    float S0 = 0.f, S1 = 0.f, S2 = 0.f;
    for (int sx = 0; sx < 7; ++sx) {
      float4 wt = WT[sx * 224 + py];
      int i0 = __float_as_int(wt.z), i1 = __float_as_int(wt.w);
      int base = sx * 7;
      S0 += wt.x * sC[base + i0]      + wt.y * sC[base + i1];
      S1 += wt.x * sC[49 + base + i0] + wt.y * sC[49 + base + i1];
      S2 += wt.x * sC[98 + base + i0] + wt.y * sC[98 + base + i1];
    }
    float W = 1e-10f + S0;
    float R = S1 / W;
    float U = S2 - S1 * S1 / W;
    out[py * 224 + b] = R;
    out[224 * 224 + py * 224 + b] = U / (W - 1.0f);
  }
}

extern "C" void kernel_launch(void* const* d_in, const int* in_sizes, int n_in,
                              void* d_out, int out_size, void* d_ws, size_t ws_size,
                              hipStream_t stream) {
  const float* x     = (const float*)d_in[0];
  const float* Wenc  = (const float*)d_in[1];
  const float* grids = (const float*)d_in[2];
  const int*   shx   = (const int*)d_in[3];
  const int*   shy   = (const int*)d_in[4];
  float* out = (float*)d_out;
  float* ws  = (float*)d_ws;

  // 1029 work + 1 WT + 29 G-zero + 1 sort + 55 M-tile blocks
  k_VT<<<NBLK_VT + 31 + 55, 256, 0, stream>>>(x, Wenc, shx, shy, ws);
  k_H2s<<<NHBLK, 256, 0, stream>>>(grids, shx, shy, ws);
  k_CO<<<224, 256, 0, stream>>>(ws, out);
}

// Round 4
// 98.531 us; speedup vs baseline: 1.2552x; 1.1678x over previous
//
#include <hip/hip_runtime.h>
#include <math.h>

// ---------------- problem constants ----------------
#define NS 3000          // 30*100 samples
#define NF 147           // 3*7*7 encoder feats
#define ND 512
#define NSIG 49          // 7x7 shift classes
#define NSAMP 4          // samples per k_H2s block (750 blocks, ~3/CU)
#define NHBLK 750        // 3000 / 4
#define NBLK_VT 1029     // 7 sy * 147 f
#define TROW 52          // padded T2 row length (49 + 3 zero pads, 16B-aligned)

// ---------------- ws layout (float offsets) ----------------
#define OFF_WT     0            // 6272 (7*224 float4: w0,w1,i0,i1)
#define OFF_FEATS  6272         // 160
#define OFF_T      236928       // T2[sig][f][52]: 49*147*52 = 374556 -> 611484
#define OFF_G      611584       // 7203
// end < 620000 floats = 2.5 MB

// weight of upsample(+reflect,+shift): output pixel p, shift sigma
__device__ __forceinline__ void wt_compute(int sigma, int p, int& i0c, int& i1c,
                                           float& w0, float& w1) {
  int k = p + sigma - 3;
  int r = k < 0 ? -k : (k > 223 ? 446 - k : k);    // np.pad 'reflect'
  float tc = (float)(2 * r - 31) * (1.0f / 64.0f); // (r+0.5)/32 - 0.5, exact
  float fl = floorf(tc);
  int i0 = (int)fl;
  float fr = tc - fl;
  i0c = min(max(i0, 0), 6);
  i1c = min(max(i0 + 1, 0), 6);
  w0 = 1.0f - fr;
  w1 = fr;
}

// Fused initV + T. Dense per-block weight tables in LDS -> b128xb128 dot4
// inner loops (no cndmask weight materialization, no scalar LDS reads).
// blocks: [0,1029) VT work; 1029 WT table; [1030,1058] zero G.
__global__ void __launch_bounds__(256) k_VT(const float* __restrict__ x,
                                            float* __restrict__ ws) {
  __shared__ __align__(16) float sX[32][36];       // x tile, 16B-aligned rows
  __shared__ __align__(16) float sVt[7][36];       // V transposed [gx][y0]
  __shared__ __align__(16) float sWXd[7][36];      // dense x-weights [gx][x0]
  __shared__ __align__(16) float sWYd[7][7][36];   // dense y-weights [sx][gy][y0]
  __shared__ float red[4];

  int b = blockIdx.x;
  int t = threadIdx.x;
  if (b >= NBLK_VT) {
    if (b == NBLK_VT) {
      float4* WT = (float4*)(ws + OFF_WT);
      for (int e = t; e < 7 * 224; e += 256) {
        int sigma = e / 224, p = e % 224;
        int i0c, i1c; float w0, w1;
        wt_compute(sigma, p, i0c, i1c, w0, w1);
        WT[e] = make_float4(w0, w1, __int_as_float(i0c), __int_as_float(i1c));
      }
    } else {
      int e = (b - NBLK_VT - 1) * 256 + t;
      if (e < 3 * 2401) ws[OFF_G + e] = 0.f;
    }
    return;
  }

  int f = b % NF;
  int sy = b / NF;
  int c = f / 49, rem = f % 49, cy = rem / 7, cx = rem % 7;

  // ---- load x tile (+ per-thread partial sum for feats) ----
  const float* xb = x + (c * 224 + cy * 32) * 224 + cx * 32;
  float psum = 0.f;
  for (int idx = t; idx < 1024; idx += 256) {
    int yy = idx >> 5, xx = idx & 31;
    float v = xb[yy * 224 + xx];
    sX[yy][xx] = v;
    psum += v;
  }

  // ---- dense weight tables ----
  if (t < 224) {                       // sWXd[gx][x0], this (sy, cx)
    int gx = t >> 5, x0 = t & 31;
    int i0, i1; float w0, w1;
    wt_compute(sy, cx * 32 + x0, i0, i1, w0, w1);
    sWXd[gx][x0] = (gx == i0 ? w0 : 0.f) + (gx == i1 ? w1 : 0.f);
  }
  for (int e = t; e < 7 * 7 * 32; e += 256) {  // sWYd[sx][gy][y0], this cy
    int sx = e / 224, r2 = e % 224, gy = r2 >> 5, y0 = r2 & 31;
    int i0, i1; float w0, w1;
    wt_compute(sx, cy * 32 + y0, i0, i1, w0, w1);
    sWYd[sx][gy][y0] = (gy == i0 ? w0 : 0.f) + (gy == i1 ? w1 : 0.f);
  }

  // ---- feats (h* input): only once per f, in the sy==0 blocks ----
  if (sy == 0) {
    float acc = psum;
    for (int off = 32; off; off >>= 1) acc += __shfl_down(acc, off);
    int wave = t >> 6, lane = t & 63;
    if (lane == 0) red[wave] = acc;
  }
  __syncthreads();
  if (sy == 0 && t == 0)
    ws[OFF_FEATS + f] = (red[0] + red[1] + red[2] + red[3]) * (1.0f / 1024.0f);

  // ---- V stage: sVt[gx][y0] = sum_x0 wx[gx][x0] * sX[y0][x0] (b128 dot4) ----
  if (t < 224) {
    int y0 = t / 7, gx = t % 7;
    const float4* wrow = (const float4*)sWXd[gx];
    const float4* xrow = (const float4*)sX[y0];
    float acc = 0.f;
    #pragma unroll
    for (int x4 = 0; x4 < 8; ++x4) {
      float4 w = wrow[x4], v = xrow[x4];
      acc = fmaf(w.x, v.x, fmaf(w.y, v.y, fmaf(w.z, v.z, fmaf(w.w, v.w, acc))));
    }
    sVt[gx][y0] = acc;
  }
  __syncthreads();

  // ---- T2 stage: 343 outputs (sx, gy, gx), layout [sig][f][52] ----
  for (int e = t; e < 343; e += 256) {
    int sx = e / 49, r2 = e % 49, gy = r2 / 7, gx = r2 % 7;
    const float4* wrow = (const float4*)sWYd[sx][gy];
    const float4* vrow = (const float4*)sVt[gx];
    float acc = 0.f;
    #pragma unroll
    for (int y4 = 0; y4 < 8; ++y4) {
      float w = 0.f; // silence unused warn pattern
      float4 w4 = wrow[y4], v4 = vrow[y4];
      (void)w;
      acc = fmaf(w4.x, v4.x, fmaf(w4.y, v4.y, fmaf(w4.z, v4.z, fmaf(w4.w, v4.w, acc))));
    }
    ws[OFF_T + ((sx * 7 + sy) * NF + f) * TROW + gy * 7 + gx] = acc * (1.0f / 1024.0f);
  }
  // zero row pads [49..51] for the 7 rows this block owns (NaN-safe vs poison)
  if (t < 21) {
    int sx = t / 3, pd = 49 + t % 3;
    ws[OFF_T + ((sx * 7 + sy) * NF + f) * TROW + pd] = 0.f;
  }
}

// R1-proven structure: F = T2[sig][f][:]@g (float4 rows), h* col + H = F@Wenc
// one pass (thread owns d=2t,2t+1), shuffle reductions, per-sample atomic flush.
__global__ void __launch_bounds__(256) k_H2s(const float* __restrict__ Wenc,
                                             const float* __restrict__ grids,
                                             const int* __restrict__ shx,
                                             const int* __restrict__ shy,
                                             float* __restrict__ ws) {
  __shared__ __align__(16) float sF[NF * NSAMP];  // [f][r], float4 per f
  __shared__ __align__(16) float sGr[NSAMP][56];  // padded rows, 16B-aligned
  __shared__ float sFeat[NF];
  __shared__ int   sSig[NSAMP];
  __shared__ float sRed[2][NSAMP][4];
  __shared__ float sRedH[4];
  __shared__ float sS[NSAMP];
  int t = threadIdx.x;
  int b = blockIdx.x;
  int i0s = b * NSAMP;
  for (int e = t; e < NSAMP * 49; e += 256) sGr[e / 49][e % 49] = grids[i0s * 49 + e];
  if (t < NSAMP * 7) sGr[t / 7][49 + t % 7] = 0.f;   // zero pads 49..55
  if (t < NSAMP) sSig[t] = shx[i0s + t] * 7 + shy[i0s + t];
  if (t < NF) sFeat[t] = ws[OFF_FEATS + t];
  __syncthreads();
  // ---- F-stage: vectorized row dot (13 float4 x 13 b128) ----
  for (int idx = t; idx < NF * NSAMP; idx += 256) {
    int r = idx / NF, f = idx - r * NF;
    const float4* T2 = (const float4*)(ws + OFF_T + (sSig[r] * NF + f) * TROW);
    const float4* gr = (const float4*)sGr[r];
    float acc = 0.f;
    #pragma unroll
    for (int g4 = 0; g4 < 13; ++g4) {
      float4 a = T2[g4], g = gr[g4];
      acc = fmaf(a.x, g.x, fmaf(a.y, g.y, fmaf(a.z, g.z, fmaf(a.w, g.w, acc))));
    }
    sF[f * NSAMP + r] = acc;
  }
  __syncthreads();
  float accA[NSAMP], accB[NSAMP];
  #pragma unroll
  for (int r = 0; r < NSAMP; ++r) { accA[r] = 0.f; accB[r] = 0.f; }
  float h0 = 0.f, h1 = 0.f;
  // thread t owns d = 2t, 2t+1 -> one float2 load per f
  const float2* W2 = (const float2*)Wenc;
  const float4* sF4 = (const float4*)sF;
  for (int f = 0; f < NF; ++f) {
    float2 w = W2[f * (ND / 2) + t];
    float fe = sFeat[f];
    h0 = fmaf(fe, w.x, h0);
    h1 = fmaf(fe, w.y, h1);
    float4 a4 = sF4[f];
    float a[NSAMP] = {a4.x, a4.y, a4.z, a4.w};
    #pragma unroll
    for (int r = 0; r < NSAMP; ++r) {
      accA[r] = fmaf(a[r], w.x, accA[r]);
      accB[r] = fmaf(a[r], w.y, accB[r]);
    }
  }
  int wave = t >> 6, lane = t & 63;
  float hq = h0 * h0 + h1 * h1;
  for (int off = 32; off; off >>= 1) hq += __shfl_down(hq, off);
  if (lane == 0) sRedH[wave] = hq;
  #pragma unroll
  for (int r = 0; r < NSAMP; ++r) {
    float np = accA[r] * h0 + accB[r] * h1;
    float sp = accA[r] * accA[r] + accB[r] * accB[r];
    for (int off = 32; off; off >>= 1) {
      np += __shfl_down(np, off);
      sp += __shfl_down(sp, off);
    }
    if (lane == 0) { sRed[0][r][wave] = np; sRed[1][r][wave] = sp; }
  }
  __syncthreads();
  if (t == 0) sRedH[0] = sqrtf(sRedH[0] + sRedH[1] + sRedH[2] + sRedH[3]);
  __syncthreads();
  if (t < NSAMP) {
    float np = sRed[0][t][0] + sRed[0][t][1] + sRed[0][t][2] + sRed[0][t][3];
    float sp = sRed[1][t][0] + sRed[1][t][1] + sRed[1][t][2] + sRed[1][t][3];
    float den = fmaxf(sRedH[0] * sqrtf(sp), 1e-8f);
    sS[t] = np / den;
  }
  __syncthreads();
  // flush this block's samples into G; k-fastest lanes -> coalesced runs
  for (int e = t; e < NSAMP * 3 * 49; e += 256) {
    int k = e % 49;
    int rp = e / 49;
    int r = rp / 3, p = rp - r * 3;
    float gv = sGr[r][k];
    if (gv != 0.f) {
      float s = sS[r];
      float add = (p == 0) ? 1.f : ((p == 1) ? s : s * s);
      atomicAdd(&ws[OFF_G + p * 2401 + sSig[r] * 49 + k], add);
    }
  }
}

// per-px-column C slice + final Welford output (one block per px)
__global__ void __launch_bounds__(256) k_CO(const float* __restrict__ ws,
                                            float* __restrict__ out) {
  __shared__ float Gl[3 * 2401];
  __shared__ float sC[NF];          // [k][sx][gy]
  int b = blockIdx.x;               // px
  int t = threadIdx.x;
  for (int e = t; e < 3 * 2401; e += 256) Gl[e] = ws[OFF_G + e];
  __syncthreads();
  const float4* WT = (const float4*)(ws + OFF_WT);
  if (t < NF) {
    int k = t / 49, r = t - k * 49;
    int sx = r / 7, gy = r % 7;
    float acc = 0.f;
    for (int sy = 0; sy < 7; ++sy) {
      float4 wt = WT[sy * 224 + b];
      int i0 = __float_as_int(wt.z), i1 = __float_as_int(wt.w);
      int base = k * 2401 + (sx * 7 + sy) * 49 + gy * 7;
      acc += wt.x * Gl[base + i0] + wt.y * Gl[base + i1];
    }
    sC[t] = acc;
  }
  __syncthreads();
  if (t < 224) {
    int py = t;
    float S0 = 0.f, S1 = 0.f, S2 = 0.f;
    for (int sx = 0; sx < 7; ++sx) {
      float4 wt = WT[sx * 224 + py];
      int i0 = __float_as_int(wt.z), i1 = __float_as_int(wt.w);
      int base = sx * 7;
      S0 += wt.x * sC[base + i0]      + wt.y * sC[base + i1];
      S1 += wt.x * sC[49 + base + i0] + wt.y * sC[49 + base + i1];
      S2 += wt.x * sC[98 + base + i0] + wt.y * sC[98 + base + i1];
    }
    float W = 1e-10f + S0;
    float R = S1 / W;
    float U = S2 - S1 * S1 / W;
    out[py * 224 + b] = R;
    out[224 * 224 + py * 224 + b] = U / (W - 1.0f);
  }
}

extern "C" void kernel_launch(void* const* d_in, const int* in_sizes, int n_in,
                              void* d_out, int out_size, void* d_ws, size_t ws_size,
                              hipStream_t stream) {
  const float* x     = (const float*)d_in[0];
  const float* Wenc  = (const float*)d_in[1];
  const float* grids = (const float*)d_in[2];
  const int*   shx   = (const int*)d_in[3];
  const int*   shy   = (const int*)d_in[4];
  float* out = (float*)d_out;
  float* ws  = (float*)d_ws;

  // 1029 work + 1 WT + 29 G-zero blocks
  k_VT<<<NBLK_VT + 30, 256, 0, stream>>>(x, ws);
  k_H2s<<<NHBLK, 256, 0, stream>>>(Wenc, grids, shx, shy, ws);
  k_CO<<<224, 256, 0, stream>>>(ws, out);
}

// Round 5
// 96.728 us; speedup vs baseline: 1.2786x; 1.0186x over previous
//
#include <hip/hip_runtime.h>
#include <math.h>

// ---------------- problem constants ----------------
#define NS 3000          // 30*100 samples
#define NF 147           // 3*7*7 encoder feats
#define ND 512
#define NSIG 49          // 7x7 shift classes
#define NSAMP 6          // samples per k_H2s block (500 blocks, ~2/CU)
#define NHBLK 500        // 3000 / 6
#define NBLK_VT 1029     // 7 sy * 147 f
#define TROW 52          // padded T2 row length (49 + 3 zero pads, 16B-aligned)

// ---------------- ws layout (float offsets) ----------------
#define OFF_WT     0            // 6272 (7*224 float4: w0,w1,i0,i1)
#define OFF_FEATS  6272         // 160
#define OFF_T      236928       // T2[sig][f][52]: 49*147*52 = 374556 -> 611484
#define OFF_G      611584       // 7203 -> 618787
#define OFF_ORD    618880       // 3000 ints (sig-sorted sample ids)
// end < 622000 floats = 2.5 MB

// weight of upsample(+reflect,+shift): output pixel p, shift sigma
__device__ __forceinline__ void wt_compute(int sigma, int p, int& i0c, int& i1c,
                                           float& w0, float& w1) {
  int k = p + sigma - 3;
  int r = k < 0 ? -k : (k > 223 ? 446 - k : k);    // np.pad 'reflect'
  float tc = (float)(2 * r - 31) * (1.0f / 64.0f); // (r+0.5)/32 - 0.5, exact
  float fl = floorf(tc);
  int i0 = (int)fl;
  float fr = tc - fl;
  i0c = min(max(i0, 0), 6);
  i1c = min(max(i0 + 1, 0), 6);
  w0 = 1.0f - fr;
  w1 = fr;
}

// Fused initV + T. Dense per-block weight tables in LDS -> b128xb128 dot4
// inner loops. blocks: [0,1029) VT work; 1029 WT table; [1030,1058] zero G;
// 1059 sig bucket-sort.
__global__ void __launch_bounds__(256) k_VT(const float* __restrict__ x,
                                            const int* __restrict__ shx,
                                            const int* __restrict__ shy,
                                            float* __restrict__ ws) {
  __shared__ __align__(16) float sX[32][36];       // x tile, 16B-aligned rows
  __shared__ __align__(16) float sVt[7][36];       // V transposed [gx][y0]
  __shared__ __align__(16) float sWXd[7][36];      // dense x-weights [gx][x0]
  __shared__ __align__(16) float sWYd[7][7][36];   // dense y-weights [sx][gy][y0]
  __shared__ float red[4];
  __shared__ int hist[64];

  int b = blockIdx.x;
  int t = threadIdx.x;
  if (b >= NBLK_VT) {
    if (b == NBLK_VT) {
      float4* WT = (float4*)(ws + OFF_WT);
      for (int e = t; e < 7 * 224; e += 256) {
        int sigma = e / 224, p = e % 224;
        int i0c, i1c; float w0, w1;
        wt_compute(sigma, p, i0c, i1c, w0, w1);
        WT[e] = make_float4(w0, w1, __int_as_float(i0c), __int_as_float(i1c));
      }
    } else if (b <= NBLK_VT + 29) {
      int e = (b - NBLK_VT - 1) * 256 + t;
      if (e < 3 * 2401) ws[OFF_G + e] = 0.f;
    } else {
      // bucket-sort sample ids by sig (G accumulation is order-free)
      if (t < 49) hist[t] = 0;
      __syncthreads();
      for (int i = t; i < NS; i += 256)
        atomicAdd(&hist[shx[i] * 7 + shy[i]], 1);
      __syncthreads();
      if (t == 0) {
        int run = 0;
        for (int s2 = 0; s2 < 49; ++s2) { int c2 = hist[s2]; hist[s2] = run; run += c2; }
      }
      __syncthreads();
      int* ord = (int*)ws + OFF_ORD;
      for (int i = t; i < NS; i += 256) {
        int s2 = shx[i] * 7 + shy[i];
        ord[atomicAdd(&hist[s2], 1)] = i;
      }
    }
    return;
  }

  int f = b % NF;
  int sy = b / NF;
  int c = f / 49, rem = f % 49, cy = rem / 7, cx = rem % 7;

  // ---- load x tile (+ per-thread partial sum for feats) ----
  const float* xb = x + (c * 224 + cy * 32) * 224 + cx * 32;
  float psum = 0.f;
  for (int idx = t; idx < 1024; idx += 256) {
    int yy = idx >> 5, xx = idx & 31;
    float v = xb[yy * 224 + xx];
    sX[yy][xx] = v;
    psum += v;
  }

  // ---- dense weight tables ----
  if (t < 224) {                       // sWXd[gx][x0], this (sy, cx)
    int gx = t >> 5, x0 = t & 31;
    int i0, i1; float w0, w1;
    wt_compute(sy, cx * 32 + x0, i0, i1, w0, w1);
    sWXd[gx][x0] = (gx == i0 ? w0 : 0.f) + (gx == i1 ? w1 : 0.f);
  }
  for (int e = t; e < 7 * 7 * 32; e += 256) {  // sWYd[sx][gy][y0], this cy
    int sx = e / 224, r2 = e % 224, gy = r2 >> 5, y0 = r2 & 31;
    int i0, i1; float w0, w1;
    wt_compute(sx, cy * 32 + y0, i0, i1, w0, w1);
    sWYd[sx][gy][y0] = (gy == i0 ? w0 : 0.f) + (gy == i1 ? w1 : 0.f);
  }

  // ---- feats (h* input): only once per f, in the sy==0 blocks ----
  if (sy == 0) {
    float acc = psum;
    for (int off = 32; off; off >>= 1) acc += __shfl_down(acc, off);
    int wave = t >> 6, lane = t & 63;
    if (lane == 0) red[wave] = acc;
  }
  __syncthreads();
  if (sy == 0 && t == 0)
    ws[OFF_FEATS + f] = (red[0] + red[1] + red[2] + red[3]) * (1.0f / 1024.0f);

  // ---- V stage: sVt[gx][y0] = sum_x0 wx[gx][x0] * sX[y0][x0] (b128 dot4) ----
  if (t < 224) {
    int y0 = t / 7, gx = t % 7;
    const float4* wrow = (const float4*)sWXd[gx];
    const float4* xrow = (const float4*)sX[y0];
    float acc = 0.f;
    #pragma unroll
    for (int x4 = 0; x4 < 8; ++x4) {
      float4 w = wrow[x4], v = xrow[x4];
      acc = fmaf(w.x, v.x, fmaf(w.y, v.y, fmaf(w.z, v.z, fmaf(w.w, v.w, acc))));
    }
    sVt[gx][y0] = acc;
  }
  __syncthreads();

  // ---- T2 stage: 343 outputs (sx, gy, gx), layout [sig][f][52] ----
  for (int e = t; e < 343; e += 256) {
    int sx = e / 49, r2 = e % 49, gy = r2 / 7, gx = r2 % 7;
    const float4* wrow = (const float4*)sWYd[sx][gy];
    const float4* vrow = (const float4*)sVt[gx];
    float acc = 0.f;
    #pragma unroll
    for (int y4 = 0; y4 < 8; ++y4) {
      float4 w4 = wrow[y4], v4 = vrow[y4];
      acc = fmaf(w4.x, v4.x, fmaf(w4.y, v4.y, fmaf(w4.z, v4.z, fmaf(w4.w, v4.w, acc))));
    }
    ws[OFF_T + ((sx * 7 + sy) * NF + f) * TROW + gy * 7 + gx] = acc * (1.0f / 1024.0f);
  }
  // zero row pads [49..51] for the 7 rows this block owns (NaN-safe vs poison)
  if (t < 21) {
    int sx = t / 3, pd = 49 + t % 3;
    ws[OFF_T + ((sx * 7 + sy) * NF + f) * TROW + pd] = 0.f;
  }
}

// R4 structure + sig-sorted samples (NSAMP=6): F = T2[sig][f][:]@g (float4,
// one L1-resident slab per uni block), H = F@Wenc one pass (d=2t,2t+1),
// shuffle reductions, uni-sig pre-accumulated flush (147 atomics vs 882).
__global__ void __launch_bounds__(256) k_H2s(const float* __restrict__ Wenc,
                                             const float* __restrict__ grids,
                                             const int* __restrict__ shx,
                                             const int* __restrict__ shy,
                                             float* __restrict__ ws) {
  __shared__ __align__(16) float sF[NF * 8];      // [f][r0..r5, pad2]
  __shared__ __align__(16) float sGr[NSAMP][56];  // padded rows, 16B-aligned
  __shared__ float sFeat[NF];
  __shared__ int   sSig[NSAMP];
  __shared__ int   sId[NSAMP];
  __shared__ float sRed[2][NSAMP][4];
  __shared__ float sRedH[4];
  __shared__ float sS[NSAMP];
  __shared__ int   sUni;
  int t = threadIdx.x;
  int b = blockIdx.x;
  int i0s = b * NSAMP;
  const int* ord = (const int*)ws + OFF_ORD;
  if (t < NSAMP) {
    int id = ord[i0s + t];
    sId[t] = id;
    sSig[t] = shx[id] * 7 + shy[id];
  }
  if (t < NF) sFeat[t] = ws[OFF_FEATS + t];
  if (t == 0) sUni = 1;
  __syncthreads();
  for (int e = t; e < NSAMP * 49; e += 256) {
    int r = e / 49, k = e % 49;
    sGr[r][k] = grids[sId[r] * 49 + k];
  }
  if (t < NSAMP * 7) sGr[t / 7][49 + t % 7] = 0.f;   // zero pads 49..55
  if (t < NSAMP && t > 0 && sSig[t] != sSig[0]) sUni = 0;
  __syncthreads();
  // ---- F-stage: vectorized row dot (13 float4 x 13 b128) ----
  for (int idx = t; idx < NF * NSAMP; idx += 256) {
    int r = idx / NF, f = idx - r * NF;
    const float4* T2 = (const float4*)(ws + OFF_T + (sSig[r] * NF + f) * TROW);
    const float4* gr = (const float4*)sGr[r];
    float acc = 0.f;
    #pragma unroll
    for (int g4 = 0; g4 < 13; ++g4) {
      float4 a = T2[g4], g = gr[g4];
      acc = fmaf(a.x, g.x, fmaf(a.y, g.y, fmaf(a.z, g.z, fmaf(a.w, g.w, acc))));
    }
    sF[f * 8 + r] = acc;
  }
  if (t < NF * 2) sF[(t / 2) * 8 + 6 + (t & 1)] = 0.f;  // zero pads
  __syncthreads();
  float accA[NSAMP], accB[NSAMP];
  #pragma unroll
  for (int r = 0; r < NSAMP; ++r) { accA[r] = 0.f; accB[r] = 0.f; }
  float h0 = 0.f, h1 = 0.f;
  // thread t owns d = 2t, 2t+1 -> one float2 load per f
  const float2* W2 = (const float2*)Wenc;
  const float4* sF4 = (const float4*)sF;
  for (int f = 0; f < NF; ++f) {
    float2 w = W2[f * (ND / 2) + t];
    float fe = sFeat[f];
    h0 = fmaf(fe, w.x, h0);
    h1 = fmaf(fe, w.y, h1);
    float4 a4 = sF4[2 * f];        // r0..r3 (broadcast)
    float4 b4 = sF4[2 * f + 1];    // r4,r5,pad,pad (broadcast)
    float a[NSAMP] = {a4.x, a4.y, a4.z, a4.w, b4.x, b4.y};
    #pragma unroll
    for (int r = 0; r < NSAMP; ++r) {
      accA[r] = fmaf(a[r], w.x, accA[r]);
      accB[r] = fmaf(a[r], w.y, accB[r]);
    }
  }
  int wave = t >> 6, lane = t & 63;
  float hq = h0 * h0 + h1 * h1;
  for (int off = 32; off; off >>= 1) hq += __shfl_down(hq, off);
  if (lane == 0) sRedH[wave] = hq;
  #pragma unroll
  for (int r = 0; r < NSAMP; ++r) {
    float np = accA[r] * h0 + accB[r] * h1;
    float sp = accA[r] * accA[r] + accB[r] * accB[r];
    for (int off = 32; off; off >>= 1) {
      np += __shfl_down(np, off);
      sp += __shfl_down(sp, off);
    }
    if (lane == 0) { sRed[0][r][wave] = np; sRed[1][r][wave] = sp; }
  }
  __syncthreads();
  if (t == 0) sRedH[0] = sqrtf(sRedH[0] + sRedH[1] + sRedH[2] + sRedH[3]);
  __syncthreads();
  if (t < NSAMP) {
    float np = sRed[0][t][0] + sRed[0][t][1] + sRed[0][t][2] + sRed[0][t][3];
    float sp = sRed[1][t][0] + sRed[1][t][1] + sRed[1][t][2] + sRed[1][t][3];
    float den = fmaxf(sRedH[0] * sqrtf(sp), 1e-8f);
    sS[t] = np / den;
  }
  __syncthreads();
  // ---- flush into G ----
  if (sUni) {
    // all samples same sig: accumulate across r, one atomic per (p,k)
    for (int e = t; e < 3 * 49; e += 256) {
      int k = e % 49, p = e / 49;
      float acc = 0.f;
      #pragma unroll
      for (int r = 0; r < NSAMP; ++r) {
        float gv = sGr[r][k];
        float s = sS[r];
        float add = (p == 0) ? 1.f : ((p == 1) ? s : s * s);
        acc += (gv != 0.f) ? add : 0.f;
      }
      if (acc != 0.f) atomicAdd(&ws[OFF_G + p * 2401 + sSig[0] * 49 + k], acc);
    }
  } else {
    for (int e = t; e < NSAMP * 3 * 49; e += 256) {
      int k = e % 49;
      int rp = e / 49;
      int r = rp / 3, p = rp - r * 3;
      float gv = sGr[r][k];
      if (gv != 0.f) {
        float s = sS[r];
        float add = (p == 0) ? 1.f : ((p == 1) ? s : s * s);
        atomicAdd(&ws[OFF_G + p * 2401 + sSig[r] * 49 + k], add);
      }
    }
  }
}

// per-px-column C slice + final Welford output (one block per px)
__global__ void __launch_bounds__(256) k_CO(const float* __restrict__ ws,
                                            float* __restrict__ out) {
  __shared__ float Gl[3 * 2401];
  __shared__ float sC[NF];          // [k][sx][gy]
  int b = blockIdx.x;               // px
  int t = threadIdx.x;
  for (int e = t; e < 3 * 2401; e += 256) Gl[e] = ws[OFF_G + e];
  __syncthreads();
  const float4* WT = (const float4*)(ws + OFF_WT);
  if (t < NF) {
    int k = t / 49, r = t - k * 49;
    int sx = r / 7, gy = r % 7;
    float acc = 0.f;
    for (int sy = 0; sy < 7; ++sy) {
      float4 wt = WT[sy * 224 + b];
      int i0 = __float_as_int(wt.z), i1 = __float_as_int(wt.w);
      int base = k * 2401 + (sx * 7 + sy) * 49 + gy * 7;
      acc += wt.x * Gl[base + i0] + wt.y * Gl[base + i1];
    }
    sC[t] = acc;
  }
  __syncthreads();
  if (t < 224) {
    int py = t;
    float S0 = 0.f, S1 = 0.f, S2 = 0.f;
    for (int sx = 0; sx < 7; ++sx) {
      float4 wt = WT[sx * 224 + py];
      int i0 = __float_as_int(wt.z), i1 = __float_as_int(wt.w);
      int base = sx * 7;
      S0 += wt.x * sC[base + i0]      + wt.y * sC[base + i1];
      S1 += wt.x * sC[49 + base + i0] + wt.y * sC[49 + base + i1];
      S2 += wt.x * sC[98 + base + i0] + wt.y * sC[98 + base + i1];
    }
    float W = 1e-10f + S0;
    float R = S1 / W;
    float U = S2 - S1 * S1 / W;
    out[py * 224 + b] = R;
    out[224 * 224 + py * 224 + b] = U / (W - 1.0f);
  }
}

extern "C" void kernel_launch(void* const* d_in, const int* in_sizes, int n_in,
                              void* d_out, int out_size, void* d_ws, size_t ws_size,
                              hipStream_t stream) {
  const float* x     = (const float*)d_in[0];
  const float* Wenc  = (const float*)d_in[1];
  const float* grids = (const float*)d_in[2];
  const int*   shx   = (const int*)d_in[3];
  const int*   shy   = (const int*)d_in[4];
  float* out = (float*)d_out;
  float* ws  = (float*)d_ws;

  // 1029 work + 1 WT + 29 G-zero + 1 sort blocks
  k_VT<<<NBLK_VT + 31, 256, 0, stream>>>(x, shx, shy, ws);
  k_H2s<<<NHBLK, 256, 0, stream>>>(Wenc, grids, shx, shy, ws);
  k_CO<<<224, 256, 0, stream>>>(ws, out);
}